// Round 1
// baseline (214.679 us; speedup 1.0000x reference)
//
#include <hip/hip_runtime.h>
#include <math.h>

#define NBATCH 64
#define NANCH_PER 3
#define NCLS 13
#define NH 76
#define NW 76
#define NPIX (NH*NW)             // 5776
#define NANCHORS (NANCH_PER*NPIX) // 17328
#define MAXT 50
#define NLC 12
#define NCH (NLC + NCLS)         // 25 channels
#define BETA_C 0.028f
#define EPS_C 1e-12f
#define NET_WH 608.0f
#define CHUNKS 23                // ceil(5776/256)

struct TRec {
  float x1, x2, y1, y2, area;   // gt box bounds + area (gx,gy in grid units; gw,gh in pixels - replicating ref)
  int   flat;                   // within-batch flat index (a*NPIX + pix), -1 if invalid
  float iou;                    // iou_t (gt vs selected pred box)
  int   cls;
  float vals[11];               // tcoord values
  float pad;
};  // 20 floats = 80 B

__device__ __forceinline__ float sigmoidf_(float x) { return 1.0f / (1.0f + __expf(-x)); }

__device__ __forceinline__ float bcef_(float p, float t) {
  float lp = __logf(fminf(fmaxf(p, EPS_C), 1.0f));
  float lq = __logf(fminf(fmaxf(1.0f - p, EPS_C), 1.0f));
  return -(t * lp + (1.0f - t) * lq);
}

// One block per batch; threads 0..49 handle targets.
__global__ void yolo_prep(const float* __restrict__ outp,
                          const float* __restrict__ target,
                          const float* __restrict__ anchors,
                          TRec* __restrict__ recs,
                          int* __restrict__ nvalid)
{
  int b = blockIdx.x;
  int t = threadIdx.x;
  bool valid = false;
  if (t < MAXT) {
    const float* tb = target + b * (MAXT * NLC) + t * NLC;
    valid = true;
    for (int s = 0; s <= t; ++s)
      valid = valid && (target[b * (MAXT * NLC) + s * NLC + 1] > 0.0f);

    float gx = tb[1] * (float)NW, gy = tb[2] * (float)NH;
    float gw = tb[10] * NET_WH,   gh = tb[11] * NET_WH;

    // best anchor (argmax of anchor-overlap IOU, first-index wins ties)
    int bn = 0; float best = -1e30f;
    for (int k = 0; k < NANCH_PER; ++k) {
      float aw = anchors[2*k], ah = anchors[2*k+1];
      float inter = fminf(gw, aw) * fminf(gh, ah);
      float r = inter / (gw * gh + aw * ah - inter);
      if (r > best) { best = r; bn = k; }
    }
    float aw = anchors[2*bn], ah = anchors[2*bn+1];

    int gi = (int)floorf(gx); gi = min(max(gi, 0), NW - 1);
    int gj = (int)floorf(gy); gj = min(max(gj, 0), NH - 1);
    int pix = gj * NW + gi;
    int flat = bn * NPIX + pix;

    // gather pred box at assigned cell
    const float* cb = outp + ((size_t)(b * NANCH_PER + bn) * NCH) * NPIX + pix;
    float px = sigmoidf_(cb[0]) + (float)gi;
    float py = sigmoidf_(cb[NPIX]) + (float)gj;
    float pw = __expf(cb[9 * NPIX]) * aw;
    float ph = __expf(cb[10 * NPIX]) * ah;

    // iou_t = iou(gt, pred_sel)
    float cw  = fminf(gx + 0.5f*gw, px + 0.5f*pw) - fmaxf(gx - 0.5f*gw, px - 0.5f*pw);
    float chh = fminf(gy + 0.5f*gh, py + 0.5f*ph) - fmaxf(gy - 0.5f*gh, py - 0.5f*ph);
    float inter = (cw > 0.0f && chh > 0.0f) ? cw * chh : 0.0f;
    float iou = inter / (gw * gh + pw * ph - inter);

    TRec r;
    r.x1 = gx - 0.5f * gw; r.x2 = gx + 0.5f * gw;
    r.y1 = gy - 0.5f * gh; r.y2 = gy + 0.5f * gh;
    r.area = gw * gh;
    r.flat = valid ? flat : -1;
    r.iou = iou;
    r.cls = (int)tb[0];
    r.vals[0] = gx - (float)gi;
    r.vals[1] = gy - (float)gj;
    #pragma unroll
    for (int k = 0; k < 7; ++k) r.vals[2 + k] = tb[3 + k];
    float sgw = valid ? gw : 1.0f, sgh = valid ? gh : 1.0f;
    r.vals[9]  = __logf(sgw / aw);
    r.vals[10] = __logf(sgh / ah);
    r.pad = 0.0f;
    recs[b * MAXT + t] = r;
  }
  unsigned long long m = __ballot(valid);
  if (threadIdx.x == 0) nvalid[b] = __popcll(m);
}

__global__ __launch_bounds__(256) void yolo_loss(
    const float* __restrict__ outp,
    const TRec* __restrict__ recs,
    const int* __restrict__ nvalid,
    const float* __restrict__ anchors,
    float* __restrict__ lossOut)
{
  __shared__ float srec[MAXT * 20];
  __shared__ int s_nv;
  __shared__ float wsum[4];

  int blk = blockIdx.x;
  int b   = blk / (NANCH_PER * CHUNKS);
  int rem = blk % (NANCH_PER * CHUNKS);
  int a   = rem / CHUNKS;
  int pix = (rem % CHUNKS) * 256 + threadIdx.x;

  const float* src = (const float*)(recs + b * MAXT);
  for (int k = threadIdx.x; k < MAXT * 20; k += 256) srec[k] = src[k];
  if (threadIdx.x == 0) s_nv = nvalid[b];
  __syncthreads();
  const TRec* R = (const TRec*)srec;

  float local = 0.0f;
  if (pix < NPIX) {
    int j = pix / NW;
    int i = pix - j * NW;
    const float* cb = outp + ((size_t)(b * NANCH_PER + a) * NCH) * NPIX + pix;

    float tx = cb[0];
    float ty = cb[NPIX];
    float tw = cb[9 * NPIX];
    float th = cb[10 * NPIX];
    float tc = cb[11 * NPIX];

    float sx = sigmoidf_(tx), sy = sigmoidf_(ty);
    float conf = sigmoidf_(tc);
    float aw = anchors[2*a], ah = anchors[2*a+1];
    float pw = __expf(tw) * aw, ph = __expf(th) * ah;
    float px = sx + (float)i, py = sy + (float)j;
    float pxl = px - 0.5f * pw, pxh = px + 0.5f * pw;
    float pyl = py - 0.5f * ph, pyh = py + 0.5f * ph;
    float parea = pw * ph;

    int myflat = a * NPIX + pix;
    int nv = s_nv;
    int match = -1;
    unsigned cmask = 0;
    bool over = false;

    for (int t = 0; t < nv; ++t) {
      const TRec& r = R[t];
      float cw  = fminf(pxh, r.x2) - fmaxf(pxl, r.x1);
      float chh = fminf(pyh, r.y2) - fmaxf(pyl, r.y1);
      float inter = (cw > 0.0f && chh > 0.0f) ? cw * chh : 0.0f;
      // iou > 0.5  <=>  3*inter > parea + tarea
      over = over || (3.0f * inter > parea + r.area);
      if (r.flat == myflat) { match = t; cmask |= (1u << r.cls); }
    }

    if (match >= 0) {
      const TRec& r = R[match];
      // conf loss (obj cell): bce(conf, iou_t)
      local += bcef_(conf, r.iou);
      // coord xy bce + wh L2
      local += bcef_(sx, r.vals[0]) + bcef_(sy, r.vals[1]);
      float d9 = tw - r.vals[9], d10 = th - r.vals[10];
      local += d9 * d9 + d10 * d10;
      // trans (channels 2..4): smooth-L1-like
      float c2 = cb[2 * NPIX], c3 = cb[3 * NPIX], c4 = cb[4 * NPIX];
      float e2 = c2 - r.vals[2], e3 = c3 - r.vals[3], e4 = c4 - r.vals[4];
      float ss = e2*e2 + e3*e3 + e4*e4;
      float dis = sqrtf(ss);
      if (dis <= BETA_C) local += 0.5f * ss / BETA_C;
      else local += fabsf(e2) + fabsf(e3) + fabsf(e4) - 0.5f * BETA_C;
      // rot (channels 5..8): normalized L1
      float c5 = cb[5 * NPIX], c6 = cb[6 * NPIX], c7 = cb[7 * NPIX], c8 = cb[8 * NPIX];
      float rn = fmaxf(sqrtf(c5*c5 + c6*c6 + c7*c7 + c8*c8), 1e-12f);
      local += fabsf(c5 / rn - r.vals[5]) + fabsf(c6 / rn - r.vals[6])
             + fabsf(c7 / rn - r.vals[7]) + fabsf(c8 / rn - r.vals[8]);
      // cls bce (stable logits form); cmask is union over colliding targets
      #pragma unroll
      for (int c = 0; c < NCLS; ++c) {
        float x = cb[(NLC + c) * NPIX];
        float tt = ((cmask >> c) & 1u) ? 1.0f : 0.0f;
        local += fmaxf(x, 0.0f) - x * tt + __logf(1.0f + __expf(-fabsf(x)));
      }
    } else if (!over) {
      // noobj cell: bce(conf, 0) = -log(clip(1-conf))
      local += -__logf(fminf(fmaxf(1.0f - conf, EPS_C), 1.0f));
    }
  }

  // reduce: wave64 shuffle, then cross-wave via LDS, one atomic per block
  for (int off = 32; off > 0; off >>= 1) local += __shfl_down(local, off, 64);
  if ((threadIdx.x & 63) == 0) wsum[threadIdx.x >> 6] = local;
  __syncthreads();
  if (threadIdx.x == 0) {
    float s = wsum[0] + wsum[1] + wsum[2] + wsum[3];
    atomicAdd(lossOut, s * (1.0f / (float)NBATCH));
  }
}

extern "C" void kernel_launch(void* const* d_in, const int* in_sizes, int n_in,
                              void* d_out, int out_size, void* d_ws, size_t ws_size,
                              hipStream_t stream) {
  const float* outp    = (const float*)d_in[0];
  const float* target  = (const float*)d_in[1];
  const float* anchors = (const float*)d_in[2];

  TRec* recs = (TRec*)d_ws;
  int* nv = (int*)((char*)d_ws + (size_t)NBATCH * MAXT * sizeof(TRec));

  hipMemsetAsync(d_out, 0, sizeof(float), stream);
  yolo_prep<<<NBATCH, 64, 0, stream>>>(outp, target, anchors, recs, nv);
  yolo_loss<<<NBATCH * NANCH_PER * CHUNKS, 256, 0, stream>>>(outp, recs, nv, anchors, (float*)d_out);
}

// Round 2
// 161.048 us; speedup vs baseline: 1.3330x; 1.3330x over previous
//
#include <hip/hip_runtime.h>
#include <math.h>

#define NBATCH 64
#define NANCH_PER 3
#define NCLS 13
#define NH 76
#define NW 76
#define NPIX (NH*NW)             // 5776
#define MAXT 50
#define NLC 12
#define NCH (NLC + NCLS)         // 25 channels
#define BETA_C 0.028f
#define EPS_C 1e-12f
#define NET_WH 608.0f
#define CHUNKS 23                // ceil(5776/256)
#define NBLK (NBATCH*NANCH_PER*CHUNKS)  // 4416
#define LOGEPS 27.6310211159285f // -log(1e-12)

struct TRec {
  float x1, x2, y1, y2;         // gt box bounds (16B-aligned for ds_read_b128)
  float area;                   // gt area
  int   flat;                   // within-batch flat index (a*NPIX + pix), -1 if invalid
  float iou;                    // iou_t (gt vs selected pred box)
  int   cls;
  float vals[11];               // tcoord values
  float pad;
};  // 20 floats = 80 B

__device__ __forceinline__ float sigmoidf_(float x) { return 1.0f / (1.0f + __expf(-x)); }

__device__ __forceinline__ float bcef_(float p, float t) {
  float lp = __logf(fminf(fmaxf(p, EPS_C), 1.0f));
  float lq = __logf(fminf(fmaxf(1.0f - p, EPS_C), 1.0f));
  return -(t * lp + (1.0f - t) * lq);
}

// One block (64 threads) per batch; thread t handles target t.
__global__ void yolo_prep(const float* __restrict__ outp,
                          const float* __restrict__ target,
                          const float* __restrict__ anchors,
                          TRec* __restrict__ recs,
                          int* __restrict__ nvalid,
                          float* __restrict__ minarr)
{
  int b = blockIdx.x;
  int t = threadIdx.x;
  const float* tb = target + b * (MAXT * NLC) + t * NLC;
  float v1 = (t < MAXT) ? tb[1] : 0.0f;
  unsigned long long vm = __ballot(v1 > 0.0f);
  bool valid = false;
  float marea = 1e30f;
  if (t < MAXT) {
    // prefix-validity: all targets s<=t have tb[s][1] > 0
    valid = ((~vm) & ((2ULL << t) - 1ULL)) == 0ULL;

    float gx = tb[1] * (float)NW, gy = tb[2] * (float)NH;
    float gw = tb[10] * NET_WH,   gh = tb[11] * NET_WH;

    // best anchor (argmax anchor-overlap IOU, first-index wins ties)
    int bn = 0; float best = -1e30f;
    for (int k = 0; k < NANCH_PER; ++k) {
      float aw = anchors[2*k], ah = anchors[2*k+1];
      float inter = fminf(gw, aw) * fminf(gh, ah);
      float r = inter / (gw * gh + aw * ah - inter);
      if (r > best) { best = r; bn = k; }
    }
    float aw = anchors[2*bn], ah = anchors[2*bn+1];

    int gi = min(max((int)floorf(gx), 0), NW - 1);
    int gj = min(max((int)floorf(gy), 0), NH - 1);
    int pixq = gj * NW + gi;
    int flat = bn * NPIX + pixq;

    // gather pred box at assigned cell
    const float* cb = outp + ((size_t)(b * NANCH_PER + bn) * NCH) * NPIX + pixq;
    float px = sigmoidf_(cb[0]) + (float)gi;
    float py = sigmoidf_(cb[NPIX]) + (float)gj;
    float pw = __expf(cb[9 * NPIX]) * aw;
    float ph = __expf(cb[10 * NPIX]) * ah;

    float cw  = fminf(gx + 0.5f*gw, px + 0.5f*pw) - fmaxf(gx - 0.5f*gw, px - 0.5f*pw);
    float chh = fminf(gy + 0.5f*gh, py + 0.5f*ph) - fmaxf(gy - 0.5f*gh, py - 0.5f*ph);
    float inter = (cw > 0.0f && chh > 0.0f) ? cw * chh : 0.0f;
    float iou = inter / (gw * gh + pw * ph - inter);

    TRec r;
    r.x1 = gx - 0.5f * gw; r.x2 = gx + 0.5f * gw;
    r.y1 = gy - 0.5f * gh; r.y2 = gy + 0.5f * gh;
    r.area = gw * gh;
    r.flat = valid ? flat : -1;
    r.iou = iou;
    r.cls = (int)tb[0];
    r.vals[0] = gx - (float)gi;
    r.vals[1] = gy - (float)gj;
    #pragma unroll
    for (int k = 0; k < 7; ++k) r.vals[2 + k] = tb[3 + k];
    float sgw = valid ? gw : 1.0f, sgh = valid ? gh : 1.0f;
    r.vals[9]  = __logf(sgw / aw);
    r.vals[10] = __logf(sgh / ah);
    r.pad = 0.0f;
    recs[b * MAXT + t] = r;
    if (valid) marea = gw * gh;
  }
  unsigned long long vm2 = __ballot(valid);
  #pragma unroll
  for (int off = 32; off > 0; off >>= 1) marea = fminf(marea, __shfl_xor(marea, off, 64));
  if (t == 0) { nvalid[b] = __popcll(vm2); minarr[b] = marea; }
}

__global__ __launch_bounds__(256) void yolo_loss(
    const float* __restrict__ outp,
    const TRec* __restrict__ recs,
    const int* __restrict__ nvalid,
    const float* __restrict__ minarr,
    const float* __restrict__ anchors,
    float* __restrict__ partial)
{
  __shared__ float srec[MAXT * 20];
  __shared__ int s_nv;
  __shared__ float s_minarea;
  __shared__ unsigned long long s_mmask;
  __shared__ float wsum[4];

  int blk = blockIdx.x;
  int b   = blk / (NANCH_PER * CHUNKS);
  int rem = blk % (NANCH_PER * CHUNKS);
  int a   = rem / CHUNKS;
  int c0  = (rem % CHUNKS) * 256;
  int pix = c0 + threadIdx.x;

  const float* src = (const float*)(recs + b * MAXT);
  for (int k = threadIdx.x; k < MAXT * 20; k += 256) srec[k] = src[k];
  if (threadIdx.x == 0) { s_nv = nvalid[b]; s_minarea = minarr[b]; }
  __syncthreads();
  const TRec* R = (const TRec*)srec;

  // per-block ballot: which targets' assigned flats fall in this block's range?
  if (threadIdx.x < 64) {
    int t = threadIdx.x;
    int lo = a * NPIX + c0, hi = lo + 256;
    bool in = (t < MAXT) && (t < s_nv);
    int f = in ? R[t].flat : -1;
    unsigned long long mm = __ballot(in && f >= lo && f < hi);
    if (t == 0) s_mmask = mm;
  }
  __syncthreads();

  float local = 0.0f;
  if (pix < NPIX) {
    const float* cb = outp + ((size_t)(b * NANCH_PER + a) * NCH) * NPIX + pix;
    float tw = cb[9 * NPIX];
    float th = cb[10 * NPIX];
    float tc = cb[11 * NPIX];
    float aw = anchors[2*a], ah = anchors[2*a+1];
    float parea = __expf(tw + th) * aw * ah;
    int myflat = a * NPIX + pix;

    // obj match: only targets whose flat is inside this block's range (usually none)
    int match = -1;
    unsigned cmask = 0;
    unsigned long long mm = s_mmask;
    while (mm) {
      int t = (int)__builtin_ctzll(mm); mm &= mm - 1;
      if (R[t].flat == myflat) { match = t; cmask |= (1u << R[t].cls); }
    }

    bool over = false;
    // screen: 3*inter > parea + tarea is impossible unless tarea < 2*parea
    if (match < 0 && 2.0f * parea > s_minarea) {
      int j = pix / NW;
      int i = pix - j * NW;
      float sx = sigmoidf_(cb[0]), sy = sigmoidf_(cb[NPIX]);
      float pw = __expf(tw) * aw, ph = __expf(th) * ah;
      float px = sx + (float)i, py = sy + (float)j;
      float pxl = px - 0.5f * pw, pxh = px + 0.5f * pw;
      float pyl = py - 0.5f * ph, pyh = py + 0.5f * ph;
      int nv = s_nv;
      for (int t = 0; t < nv; ++t) {
        float x1 = R[t].x1, x2 = R[t].x2, y1 = R[t].y1, y2 = R[t].y2;
        float ta = R[t].area;
        float cw  = fminf(pxh, x2) - fmaxf(pxl, x1);
        float chh = fminf(pyh, y2) - fmaxf(pyl, y1);
        float inter = (cw > 0.0f && chh > 0.0f) ? cw * chh : 0.0f;
        over = over || (3.0f * inter > parea + ta);
      }
    }

    if (match >= 0) {
      int j = pix / NW;
      int i = pix - j * NW;
      float sx = sigmoidf_(cb[0]), sy = sigmoidf_(cb[NPIX]);
      float conf = sigmoidf_(tc);
      const TRec& r = R[match];
      // conf loss (obj cell): bce(conf, iou_t)
      local += bcef_(conf, r.iou);
      // coord xy bce + wh L2
      local += bcef_(sx, r.vals[0]) + bcef_(sy, r.vals[1]);
      float d9 = tw - r.vals[9], d10 = th - r.vals[10];
      local += d9 * d9 + d10 * d10;
      // trans (channels 2..4): smooth-L1-like
      float c2 = cb[2 * NPIX], c3 = cb[3 * NPIX], c4 = cb[4 * NPIX];
      float e2 = c2 - r.vals[2], e3 = c3 - r.vals[3], e4 = c4 - r.vals[4];
      float ss = e2*e2 + e3*e3 + e4*e4;
      float dis = sqrtf(ss);
      if (dis <= BETA_C) local += 0.5f * ss / BETA_C;
      else local += fabsf(e2) + fabsf(e3) + fabsf(e4) - 0.5f * BETA_C;
      // rot (channels 5..8): normalized L1
      float c5 = cb[5 * NPIX], c6 = cb[6 * NPIX], c7 = cb[7 * NPIX], c8 = cb[8 * NPIX];
      float rn = fmaxf(sqrtf(c5*c5 + c6*c6 + c7*c7 + c8*c8), 1e-12f);
      local += fabsf(c5 / rn - r.vals[5]) + fabsf(c6 / rn - r.vals[6])
             + fabsf(c7 / rn - r.vals[7]) + fabsf(c8 / rn - r.vals[8]);
      // cls bce (stable logits form); cmask is union over colliding targets
      #pragma unroll
      for (int c = 0; c < NCLS; ++c) {
        float x = cb[(NLC + c) * NPIX];
        float tt = ((cmask >> c) & 1u) ? 1.0f : 0.0f;
        local += fmaxf(x, 0.0f) - x * tt + __logf(1.0f + __expf(-fabsf(x)));
      }
    } else if (!over) {
      // noobj cell: bce(sigmoid(tc), 0) = min(softplus(tc), -log(EPS))
      float e = __expf(tc);
      local += fminf(__logf(1.0f + e), LOGEPS);
    }
  }

  // reduce: wave64 shuffle, then cross-wave via LDS, one partial per block
  #pragma unroll
  for (int off = 32; off > 0; off >>= 1) local += __shfl_down(local, off, 64);
  if ((threadIdx.x & 63) == 0) wsum[threadIdx.x >> 6] = local;
  __syncthreads();
  if (threadIdx.x == 0) partial[blk] = wsum[0] + wsum[1] + wsum[2] + wsum[3];
}

__global__ __launch_bounds__(256) void yolo_final(const float* __restrict__ partial,
                                                  float* __restrict__ out)
{
  __shared__ float w[4];
  float s = 0.0f;
  for (int i = threadIdx.x; i < NBLK; i += 256) s += partial[i];
  #pragma unroll
  for (int off = 32; off > 0; off >>= 1) s += __shfl_down(s, off, 64);
  if ((threadIdx.x & 63) == 0) w[threadIdx.x >> 6] = s;
  __syncthreads();
  if (threadIdx.x == 0) out[0] = (w[0] + w[1] + w[2] + w[3]) * (1.0f / (float)NBATCH);
}

extern "C" void kernel_launch(void* const* d_in, const int* in_sizes, int n_in,
                              void* d_out, int out_size, void* d_ws, size_t ws_size,
                              hipStream_t stream) {
  const float* outp    = (const float*)d_in[0];
  const float* target  = (const float*)d_in[1];
  const float* anchors = (const float*)d_in[2];

  char* ws = (char*)d_ws;
  TRec*  recs    = (TRec*)ws;                                   // 64*50*80 = 256000 B
  int*   nv      = (int*)(ws + 256000);                         // 256 B
  float* minarr  = (float*)(ws + 256000 + 256);                 // 256 B
  float* partial = (float*)(ws + 256000 + 512);                 // 4416*4 = 17664 B

  yolo_prep<<<NBATCH, 64, 0, stream>>>(outp, target, anchors, recs, nv, minarr);
  yolo_loss<<<NBLK, 256, 0, stream>>>(outp, recs, nv, minarr, anchors, partial);
  yolo_final<<<1, 256, 0, stream>>>(partial, (float*)d_out);
}